// Round 6
// baseline (555.803 us; speedup 1.0000x reference)
//
#include <hip/hip_runtime.h>
#include <hip/hip_bf16.h>
#include <cstdint>
#include <cstddef>

#define BLK 256     // pack/sum/final block size
#define DG 12
#define NSLOT 30    // 12 rbfL + normL + 12 rbfR + normR + d2L + idxL + d2R + idxR

static constexpr float EPS_ = 0.01f;
// exp(-d/sigma) == exp2(c2 * d), c2 = -1/(sigma*ln2), sigma = 2.5
static constexpr float C2_ = -0.57707801635558534f;

typedef __attribute__((ext_vector_type(2))) float v2f;   // packed fp32 (VOP3P)
typedef __attribute__((ext_vector_type(8))) short v8s;   // 8 bf16 (MFMA A/B frag)
typedef __attribute__((ext_vector_type(4))) float v4f;   // MFMA C/D frag

// ---------------------------------------------------------------------------
// Kernel 0: pack into pair-interleaved streams (P = point pairs = 16T).
//  pk1p[(pair*2+side)] -> 2 float4: {x0,x1,y0,y1}, {z0,z1,h0,h1}, h = |p|^2/2
//  pkp[pair] -> 3 float4: {s1:x0,x1,y0,y1}, {s2:x0,x1,y0,y1}, {s1:z0,z1, s2:z0,z1}
//  fpk[side][tile][lane] -> int4 B-fragment of F = [s_x(12), 1.0] in bf16
// Pads (n>=N): pos 1e9 (argmin never wins; w==0), F=0.
// ---------------------------------------------------------------------------
__global__ __launch_bounds__(BLK) void pip_pack(
    const float* __restrict__ g1_pos, const float* __restrict__ g2_pos,
    const float* __restrict__ s1_v,   const float* __restrict__ s1_x,
    const float* __restrict__ s2_v,   const float* __restrict__ s2_x,
    float4* __restrict__ pk1p, float4* __restrict__ pkp, int4* __restrict__ fpk,
    int N, int T)
{
#pragma clang fp contract(off)
    const int P = T * 16;
    const int tid = blockIdx.x * BLK + threadIdx.x;
    if (tid < 2 * P) {                         // pk1p
        const int pr = tid >> 1;
        const float* src = (tid & 1) ? g2_pos : g1_pos;
        const int n0 = 2 * pr, n1 = 2 * pr + 1;
        float x0 = 1e9f, y0 = 1e9f, z0 = 1e9f, h0 = 1.5e18f;
        float x1 = 1e9f, y1 = 1e9f, z1 = 1e9f, h1 = 1.5e18f;
        if (n0 < N) {
            x0 = src[3 * n0]; y0 = src[3 * n0 + 1]; z0 = src[3 * n0 + 2];
            h0 = 0.5f * ((x0 * x0 + y0 * y0) + z0 * z0);   // exact half of ref |p|^2
        }
        if (n1 < N) {
            x1 = src[3 * n1]; y1 = src[3 * n1 + 1]; z1 = src[3 * n1 + 2];
            h1 = 0.5f * ((x1 * x1 + y1 * y1) + z1 * z1);
        }
        pk1p[(size_t)tid * 2 + 0] = make_float4(x0, x1, y0, y1);
        pk1p[(size_t)tid * 2 + 1] = make_float4(z0, z1, h0, h1);
    } else if (tid < 3 * P) {                  // pkp
        const int pr = tid - 2 * P;
        const int n0 = 2 * pr, n1 = 2 * pr + 1;
        float a0 = 1e9f, b0 = 1e9f, c0 = 1e9f, a1 = 1e9f, b1 = 1e9f, c1 = 1e9f;
        float d0 = 1e9f, e0 = 1e9f, f0 = 1e9f, d1 = 1e9f, e1 = 1e9f, f1 = 1e9f;
        if (n0 < N) { a0 = s1_v[3 * n0]; b0 = s1_v[3 * n0 + 1]; c0 = s1_v[3 * n0 + 2];
                      d0 = s2_v[3 * n0]; e0 = s2_v[3 * n0 + 1]; f0 = s2_v[3 * n0 + 2]; }
        if (n1 < N) { a1 = s1_v[3 * n1]; b1 = s1_v[3 * n1 + 1]; c1 = s1_v[3 * n1 + 2];
                      d1 = s2_v[3 * n1]; e1 = s2_v[3 * n1 + 1]; f1 = s2_v[3 * n1 + 2]; }
        pkp[(size_t)pr * 3 + 0] = make_float4(a0, a1, b0, b1);
        pkp[(size_t)pr * 3 + 1] = make_float4(d0, d1, e0, e1);
        pkp[(size_t)pr * 3 + 2] = make_float4(c0, c1, f0, f1);
    } else {                                   // fpk B-fragments
        const int u = tid - 3 * P;
        if (u < 128 * T) {
            const int side = u / (64 * T);
            const int r = u - side * 64 * T;
            const int t = r >> 6;
            const int ln = r & 63;
            const float* X = side ? s2_x : s1_x;
            const int nb = 32 * t + ((ln >> 4) << 3);
            const int feat = ln & 15;
            int w[4];
#pragma unroll
            for (int d = 0; d < 4; ++d) {
                const int n0 = nb + 2 * d, n1 = nb + 2 * d + 1;
                const float f0 = (n0 < N) ? (feat < 12 ? X[(size_t)n0 * DG + feat] : (feat == 12 ? 1.f : 0.f)) : 0.f;
                const float f1 = (n1 < N) ? (feat < 12 ? X[(size_t)n1 * DG + feat] : (feat == 12 ? 1.f : 0.f)) : 0.f;
                __hip_bfloat162 h = __float22bfloat162_rn(make_float2(f0, f1));
                __builtin_memcpy(&w[d], &h, 4);
            }
            fpk[((size_t)side * T + t) * 64 + ln] = make_int4(w[0], w[1], w[2], w[3]);
        }
    }
}

// ---------------------------------------------------------------------------
// Kernel 1: partial scans. Block = 128 thr = 2 waves; each wave owns 64 queries.
// Per 32-point tile: vector loads hoisted first (latency hidden under argmin),
// argmin on packed fp32 pairs at half scale (bit-identical ordering to ref),
// RBF w's built packed-fp32 directly in MFMA A-frag order -> 8 MFMAs. No LDS.
// ---------------------------------------------------------------------------
__global__ __launch_bounds__(128, 3) void pip_partial(
    const float* __restrict__ locs_l, const float* __restrict__ locs_r,
    const float4* __restrict__ pk1p,  const float4* __restrict__ pkp,
    const int4* __restrict__ fpk,
    float* __restrict__ part, int L, int T, int CT)
{
#pragma clang fp contract(off)   // plain mul/add unfused; fma only where written
    const int lane = threadIdx.x & 63;
    const int wv = threadIdx.x >> 6;
    const int qbase = blockIdx.x * 128 + wv * 64;
    const int lq = qbase + lane;          // this lane's argmin query (L % 128 == 0)

    // argmin query data (half-scale |q|^2)
    const float qlx = locs_l[3 * lq + 0];
    const float qly = locs_l[3 * lq + 1];
    const float qlz = locs_l[3 * lq + 2];
    const float qrx = locs_r[3 * lq + 0];
    const float qry = locs_r[3 * lq + 1];
    const float qrz = locs_r[3 * lq + 2];
    const float nqhL = 0.5f * ((qlx * qlx + qly * qly) + qlz * qlz);
    const float nqhR = 0.5f * ((qrx * qrx + qry * qry) + qrz * qrz);
    // splats for packed fma operands
    const v2f qlx2 = {qlx, qlx}, qly2 = {qly, qly}, qlz2 = {qlz, qlz};
    const v2f qrx2 = {qrx, qrx}, qry2 = {qry, qry}, qrz2 = {qrz, qrz};

    // RBF fragment-role queries: q = qbase + 16*mt + (lane&15)
    float qmlx[4], qmly[4], qmlz[4], qmrx[4], qmry[4], qmrz[4];
#pragma unroll
    for (int mt = 0; mt < 4; ++mt) {
        const int qm = qbase + 16 * mt + (lane & 15);
        qmlx[mt] = locs_l[3 * qm + 0];
        qmly[mt] = locs_l[3 * qm + 1];
        qmlz[mt] = locs_l[3 * qm + 2];
        qmrx[mt] = locs_r[3 * qm + 0];
        qmry[mt] = locs_r[3 * qm + 1];
        qmrz[mt] = locs_r[3 * qm + 2];
    }

    v4f cL[4], cR[4];
#pragma unroll
    for (int mt = 0; mt < 4; ++mt) { cL[mt] = (v4f)0.f; cR[mt] = (v4f)0.f; }

    float bdL = 3.4e38f, bdR = 3.4e38f;
    unsigned biL = 0u, biR = 0u;

    const int t0 = blockIdx.y * CT;
    const int t1 = (t0 + CT < T) ? (t0 + CT) : T;

    for (int tg = t0; tg < t1; ++tg) {
        // ---- vector loads first: their latency hides under the argmin phase
        const int pg0 = tg * 16 + ((lane >> 4) << 2);   // this lane's 4 point-pairs
        float4 F0[4], F1[4], F2[4];
#pragma unroll
        for (int dp = 0; dp < 4; ++dp) {
            F0[dp] = pkp[(size_t)(pg0 + dp) * 3 + 0];
            F1[dp] = pkp[(size_t)(pg0 + dp) * 3 + 1];
            F2[dp] = pkp[(size_t)(pg0 + dp) * 3 + 2];
        }
        const v8s b1 = ((const v8s*)fpk)[(size_t)tg * 64 + lane];
        const v8s b2 = ((const v8s*)fpk)[((size_t)T + tg) * 64 + lane];

        // ---- argmin over 16 packed pairs (uniform addresses -> scalar loads)
        const int prb = tg * 16;
#pragma unroll 4
        for (int j = 0; j < 16; ++j) {
            const float4 XY1 = pk1p[(size_t)(prb + j) * 4 + 0];
            const float4 ZH1 = pk1p[(size_t)(prb + j) * 4 + 1];
            const float4 XY2 = pk1p[(size_t)(prb + j) * 4 + 2];
            const float4 ZH2 = pk1p[(size_t)(prb + j) * 4 + 3];
            {   // left: d2/2 = (|q|^2/2 + |p|^2/2) - dot ; ordering == ref
                const v2f xx = {XY1.x, XY1.y}, yy = {XY1.z, XY1.w};
                const v2f zz = {ZH1.x, ZH1.y}, hh = {ZH1.z, ZH1.w};
                const v2f dot = __builtin_elementwise_fma(qlz2, zz,
                                  __builtin_elementwise_fma(qly2, yy, qlx2 * xx));
                const v2f d2 = (nqhL + hh) - dot;
                const bool c0 = d2.x < bdL;
                bdL = c0 ? d2.x : bdL;
                biL = c0 ? (unsigned)(2 * (prb + j)) : biL;
                const bool c1 = d2.y < bdL;
                bdL = c1 ? d2.y : bdL;
                biL = c1 ? (unsigned)(2 * (prb + j) + 1) : biL;
            }
            {   // right
                const v2f xx = {XY2.x, XY2.y}, yy = {XY2.z, XY2.w};
                const v2f zz = {ZH2.x, ZH2.y}, hh = {ZH2.z, ZH2.w};
                const v2f dot = __builtin_elementwise_fma(qrz2, zz,
                                  __builtin_elementwise_fma(qry2, yy, qrx2 * xx));
                const v2f d2 = (nqhR + hh) - dot;
                const bool c0 = d2.x < bdR;
                bdR = c0 ? d2.x : bdR;
                biR = c0 ? (unsigned)(2 * (prb + j)) : biR;
                const bool c1 = d2.y < bdR;
                bdR = c1 ? d2.y : bdR;
                biR = c1 ? (unsigned)(2 * (prb + j) + 1) : biR;
            }
        }

        // ---- RBF: packed distances, w's in A-frag order
        union AF { int i[4]; v8s s; };
        AF af1[4], af2[4];
#pragma unroll
        for (int dp = 0; dp < 4; ++dp) {
            const v2f x1 = {F0[dp].x, F0[dp].y}, y1 = {F0[dp].z, F0[dp].w};
            const v2f x2 = {F1[dp].x, F1[dp].y}, y2 = {F1[dp].z, F1[dp].w};
            const v2f z1 = {F2[dp].x, F2[dp].y}, z2 = {F2[dp].z, F2[dp].w};
#pragma unroll
            for (int mt = 0; mt < 4; ++mt) {
                {   // side 1 (left)
                    const v2f dx = qmlx[mt] - x1, dy = qmly[mt] - y1, dz = qmlz[mt] - z1;
                    const v2f d2v = __builtin_elementwise_fma(dx, dx,
                                      __builtin_elementwise_fma(dy, dy, dz * dz));
                    const float w0 = __builtin_amdgcn_exp2f(C2_ * __builtin_amdgcn_sqrtf(d2v.x));
                    const float w1 = __builtin_amdgcn_exp2f(C2_ * __builtin_amdgcn_sqrtf(d2v.y));
                    __hip_bfloat162 h = __float22bfloat162_rn(make_float2(w0, w1));
                    __builtin_memcpy(&af1[mt].i[dp], &h, 4);
                }
                {   // side 2 (right)
                    const v2f dx = qmrx[mt] - x2, dy = qmry[mt] - y2, dz = qmrz[mt] - z2;
                    const v2f d2v = __builtin_elementwise_fma(dx, dx,
                                      __builtin_elementwise_fma(dy, dy, dz * dz));
                    const float w0 = __builtin_amdgcn_exp2f(C2_ * __builtin_amdgcn_sqrtf(d2v.x));
                    const float w1 = __builtin_amdgcn_exp2f(C2_ * __builtin_amdgcn_sqrtf(d2v.y));
                    __hip_bfloat162 h = __float22bfloat162_rn(make_float2(w0, w1));
                    __builtin_memcpy(&af2[mt].i[dp], &h, 4);
                }
            }
        }

        // ---- 8 MFMAs
#pragma unroll
        for (int mt = 0; mt < 4; ++mt) {
            cL[mt] = __builtin_amdgcn_mfma_f32_16x16x32_bf16(af1[mt].s, b1, cL[mt], 0, 0, 0);
            cR[mt] = __builtin_amdgcn_mfma_f32_16x16x32_bf16(af2[mt].s, b2, cR[mt], 0, 0, 0);
        }
    }

    // ---- store partials
    float* pbase = part + (size_t)(blockIdx.y * NSLOT) * (size_t)L;
    const int feat = lane & 15;
    if (feat < 13) {
        // C/D layout: col(=feat)=lane&15, row(=q within 16-tile)=(lane>>4)*4+reg
#pragma unroll
        for (int mt = 0; mt < 4; ++mt)
#pragma unroll
            for (int r = 0; r < 4; ++r) {
                const int q = qbase + 16 * mt + ((lane >> 4) << 2) + r;
                pbase[(size_t)feat * L + q]        = cL[mt][r];
                pbase[(size_t)(13 + feat) * L + q] = cR[mt][r];
            }
    }
    unsigned* pu = (unsigned*)pbase;
    pu[(size_t)26 * L + lq] = __float_as_uint(bdL);   // d2h > 0 -> bit-ordered
    pu[(size_t)27 * L + lq] = biL;
    pu[(size_t)28 * L + lq] = __float_as_uint(bdR);
    pu[(size_t)29 * L + lq] = biR;
}

// ---------------------------------------------------------------------------
// Kernel 2: wide reduction of SC chunks -> 1. blockIdx.y = task:
// 0..25 float-sum slots, 26 -> u64-min of (26,27), 27 -> u64-min of (28,29).
// ---------------------------------------------------------------------------
__global__ __launch_bounds__(BLK) void pip_sum(
    const float* __restrict__ part, float* __restrict__ red, int L, int SC)
{
    const int l = blockIdx.x * BLK + threadIdx.x;
    const int t = blockIdx.y;
    if (l >= L) return;
    if (t < 26) {
        float acc = 0.f;
        for (int s = 0; s < SC; ++s)
            acc += part[((size_t)s * NSLOT + t) * (size_t)L + (size_t)l];
        red[(size_t)t * L + (size_t)l] = acc;
    } else {
        const int base = (t == 26) ? 26 : 28;
        unsigned long long key = ~0ull;
        for (int s = 0; s < SC; ++s) {
            const unsigned* pu = (const unsigned*)(part + (size_t)(s * NSLOT) * (size_t)L);
            const unsigned d = pu[(size_t)base * L + (size_t)l];
            const unsigned i = pu[(size_t)(base + 1) * L + (size_t)l];
            const unsigned long long c = ((unsigned long long)d << 32) | (unsigned long long)i;
            key = c < key ? c : key;
        }
        unsigned* ru = (unsigned*)red;
        ru[(size_t)base * L + (size_t)l] = (unsigned)(key >> 32);
        ru[(size_t)(base + 1) * L + (size_t)l] = (unsigned)key;
    }
}

__device__ __forceinline__ float tanh_pos(float x) {
    const float t = __expf(-2.f * x);
    return (1.f - t) / (1.f + t);
}

// ---------------------------------------------------------------------------
// Kernel 3: gather nearest-node feats + 50->50->1 MLP. Thread = one query l.
// ---------------------------------------------------------------------------
__global__ __launch_bounds__(BLK) void pip_final(
    const float* __restrict__ red,
    const float* __restrict__ g1_x, const float* __restrict__ g2_x,
    const float* __restrict__ W1, const float* __restrict__ b1,
    const float* __restrict__ W2, const float* __restrict__ b2,
    float* __restrict__ out, int L)
{
#pragma clang fp contract(off)
    const int l = blockIdx.x * BLK + threadIdx.x;
    if (l >= L) return;

    const unsigned* ru = (const unsigned*)red;
    const unsigned idxL = ru[(size_t)27 * L + (size_t)l];
    const unsigned idxR = ru[(size_t)29 * L + (size_t)l];
    const float normL = red[(size_t)12 * L + (size_t)l] + EPS_;
    const float normR = red[(size_t)25 * L + (size_t)l] + EPS_;

    float x[50];
    {
        const float4* f = (const float4*)(g1_x + (size_t)idxL * DG);
        const float4 f0 = f[0], f1 = f[1], f2 = f[2];
        x[0] = f0.x; x[1] = f0.y; x[2]  = f0.z; x[3]  = f0.w;
        x[4] = f1.x; x[5] = f1.y; x[6]  = f1.z; x[7]  = f1.w;
        x[8] = f2.x; x[9] = f2.y; x[10] = f2.z; x[11] = f2.w;
    }
#pragma unroll
    for (int k = 0; k < DG; ++k) x[12 + k] = red[(size_t)k * L + (size_t)l] / normL;
    x[24] = tanh_pos(normL);
    {
        const float4* f = (const float4*)(g2_x + (size_t)idxR * DG);
        const float4 f0 = f[0], f1 = f[1], f2 = f[2];
        x[25] = f0.x; x[26] = f0.y; x[27] = f0.z; x[28] = f0.w;
        x[29] = f1.x; x[30] = f1.y; x[31] = f1.z; x[32] = f1.w;
        x[33] = f2.x; x[34] = f2.y; x[35] = f2.z; x[36] = f2.w;
    }
#pragma unroll
    for (int k = 0; k < DG; ++k) x[37 + k] = red[(size_t)(13 + k) * L + (size_t)l] / normR;
    x[49] = tanh_pos(normR);

    float h[50];
#pragma unroll
    for (int j = 0; j < 50; ++j) h[j] = b1[j];
#pragma unroll
    for (int k = 0; k < 50; ++k) {
        const float xk = x[k];
#pragma unroll
        for (int j = 0; j < 50; ++j) h[j] = fmaf(xk, W1[k * 50 + j], h[j]);
    }
    float o = b2[0];
#pragma unroll
    for (int j = 0; j < 50; ++j) o = fmaf(fmaxf(h[j], 0.f), W2[j], o);
    out[l] = o;
}

// ---------------------------------------------------------------------------
extern "C" void kernel_launch(void* const* d_in, const int* in_sizes, int n_in,
                              void* d_out, int out_size, void* d_ws, size_t ws_size,
                              hipStream_t stream) {
    const float* locs_l = (const float*)d_in[0];
    const float* locs_r = (const float*)d_in[1];
    const float* g1_pos = (const float*)d_in[2];
    const float* g1_x   = (const float*)d_in[3];
    const float* g2_pos = (const float*)d_in[4];
    const float* g2_x   = (const float*)d_in[5];
    const float* s1_v   = (const float*)d_in[6];
    const float* s1_x   = (const float*)d_in[7];
    const float* s2_v   = (const float*)d_in[8];
    const float* s2_x   = (const float*)d_in[9];
    const float* W1     = (const float*)d_in[10];
    const float* b1     = (const float*)d_in[11];
    const float* W2     = (const float*)d_in[12];
    const float* b2     = (const float*)d_in[13];
    float* out = (float*)d_out;
    float* ws  = (float*)d_ws;

    const int L = in_sizes[0] / 3;   // 4096
    const int N = in_sizes[2] / 3;   // 40000
    const int T = (N + 31) / 32;     // 32-point tiles (1250, exact)

    // ws layout (floats): [pk1p: 256T][pkp: 192T][fpk: 512T][part: SC*30*L][red: 30*L]
    const size_t o_pkp  = (size_t)256 * T;
    const size_t o_fpk  = (size_t)448 * T;
    const size_t o_part = (size_t)960 * T;

    // chunk size in tiles; SC chunks -> grid.y ~63 (grid 32x63 = 2016 blocks).
    int CT = 20;
    int SC = (T + CT - 1) / CT;
    while (CT < T) {
        const size_t need = (o_part + (size_t)(SC + 1) * NSLOT * (size_t)L) * sizeof(float);
        if (need <= ws_size) break;
        CT *= 2;
        SC = (T + CT - 1) / CT;
    }

    float4* pk1p = (float4*)ws;
    float4* pkp  = (float4*)(ws + o_pkp);
    int4*   fpk  = (int4*)(ws + o_fpk);
    float*  part = ws + o_part;
    float*  red  = part + (size_t)SC * NSLOT * (size_t)L;

    const int ptasks = 48 * T + 128 * T;    // 3P + 128T, P = 16T
    pip_pack<<<dim3((ptasks + BLK - 1) / BLK), dim3(BLK), 0, stream>>>(
        g1_pos, g2_pos, s1_v, s1_x, s2_v, s2_x, pk1p, pkp, fpk, N, T);

    pip_partial<<<dim3(L / 128, SC), dim3(128), 0, stream>>>(
        locs_l, locs_r, pk1p, pkp, fpk, part, L, T, CT);

    const int lblocks = (L + BLK - 1) / BLK;
    pip_sum<<<dim3(lblocks, 28), dim3(BLK), 0, stream>>>(part, red, L, SC);

    pip_final<<<dim3(lblocks), dim3(BLK), 0, stream>>>(
        red, g1_x, g2_x, W1, b1, W2, b2, out, L);
}

// Round 7
// 379.878 us; speedup vs baseline: 1.4631x; 1.4631x over previous
//
#include <hip/hip_runtime.h>
#include <hip/hip_bf16.h>
#include <cstdint>
#include <cstddef>

#define BLK 256     // pack/sum/final block size
#define DG 12
#define NSLOT 30    // 12 rbfL + normL + 12 rbfR + normR + d2L + idxL + d2R + idxR

static constexpr float EPS_ = 0.01f;
// exp(-d/sigma) == exp2(c2 * d), c2 = -1/(sigma*ln2), sigma = 2.5
static constexpr float C2_ = -0.57707801635558534f;

typedef __attribute__((ext_vector_type(2))) float v2f;   // packed fp32 (VOP3P)
typedef __attribute__((ext_vector_type(8))) short v8s;   // 8 bf16 (MFMA A/B frag)
typedef __attribute__((ext_vector_type(4))) float v4f;   // MFMA C/D frag

// ---------------------------------------------------------------------------
// Kernel 0: pack into pair-interleaved streams (P = point pairs = 16T).
//  pk1p[(pair*2+side)] -> 2 float4: {x0,x1,y0,y1}, {z0,z1,h0,h1}, h = |p|^2/2
//  pkp[pair] -> 3 float4: {s1:x0,x1,y0,y1}, {s2:x0,x1,y0,y1}, {s1:z0,z1, s2:z0,z1}
//  fpk[side][tile][lane] -> int4 B-fragment of F = [s_x(12), 1.0] in bf16
// Pads (n>=N): pos 1e9 (argmin never wins; w==0), F=0.
// ---------------------------------------------------------------------------
__global__ __launch_bounds__(BLK) void pip_pack(
    const float* __restrict__ g1_pos, const float* __restrict__ g2_pos,
    const float* __restrict__ s1_v,   const float* __restrict__ s1_x,
    const float* __restrict__ s2_v,   const float* __restrict__ s2_x,
    float4* __restrict__ pk1p, float4* __restrict__ pkp, int4* __restrict__ fpk,
    int N, int T)
{
#pragma clang fp contract(off)
    const int P = T * 16;
    const int tid = blockIdx.x * BLK + threadIdx.x;
    if (tid < 2 * P) {                         // pk1p
        const int pr = tid >> 1;
        const float* src = (tid & 1) ? g2_pos : g1_pos;
        const int n0 = 2 * pr, n1 = 2 * pr + 1;
        float x0 = 1e9f, y0 = 1e9f, z0 = 1e9f, h0 = 1.5e18f;
        float x1 = 1e9f, y1 = 1e9f, z1 = 1e9f, h1 = 1.5e18f;
        if (n0 < N) {
            x0 = src[3 * n0]; y0 = src[3 * n0 + 1]; z0 = src[3 * n0 + 2];
            h0 = 0.5f * ((x0 * x0 + y0 * y0) + z0 * z0);   // exact half of ref |p|^2
        }
        if (n1 < N) {
            x1 = src[3 * n1]; y1 = src[3 * n1 + 1]; z1 = src[3 * n1 + 2];
            h1 = 0.5f * ((x1 * x1 + y1 * y1) + z1 * z1);
        }
        pk1p[(size_t)tid * 2 + 0] = make_float4(x0, x1, y0, y1);
        pk1p[(size_t)tid * 2 + 1] = make_float4(z0, z1, h0, h1);
    } else if (tid < 3 * P) {                  // pkp
        const int pr = tid - 2 * P;
        const int n0 = 2 * pr, n1 = 2 * pr + 1;
        float a0 = 1e9f, b0 = 1e9f, c0 = 1e9f, a1 = 1e9f, b1 = 1e9f, c1 = 1e9f;
        float d0 = 1e9f, e0 = 1e9f, f0 = 1e9f, d1 = 1e9f, e1 = 1e9f, f1 = 1e9f;
        if (n0 < N) { a0 = s1_v[3 * n0]; b0 = s1_v[3 * n0 + 1]; c0 = s1_v[3 * n0 + 2];
                      d0 = s2_v[3 * n0]; e0 = s2_v[3 * n0 + 1]; f0 = s2_v[3 * n0 + 2]; }
        if (n1 < N) { a1 = s1_v[3 * n1]; b1 = s1_v[3 * n1 + 1]; c1 = s1_v[3 * n1 + 2];
                      d1 = s2_v[3 * n1]; e1 = s2_v[3 * n1 + 1]; f1 = s2_v[3 * n1 + 2]; }
        pkp[(size_t)pr * 3 + 0] = make_float4(a0, a1, b0, b1);
        pkp[(size_t)pr * 3 + 1] = make_float4(d0, d1, e0, e1);
        pkp[(size_t)pr * 3 + 2] = make_float4(c0, c1, f0, f1);
    } else {                                   // fpk B-fragments
        const int u = tid - 3 * P;
        if (u < 128 * T) {
            const int side = u / (64 * T);
            const int r = u - side * 64 * T;
            const int t = r >> 6;
            const int ln = r & 63;
            const float* X = side ? s2_x : s1_x;
            const int nb = 32 * t + ((ln >> 4) << 3);
            const int feat = ln & 15;
            int w[4];
#pragma unroll
            for (int d = 0; d < 4; ++d) {
                const int n0 = nb + 2 * d, n1 = nb + 2 * d + 1;
                const float f0 = (n0 < N) ? (feat < 12 ? X[(size_t)n0 * DG + feat] : (feat == 12 ? 1.f : 0.f)) : 0.f;
                const float f1 = (n1 < N) ? (feat < 12 ? X[(size_t)n1 * DG + feat] : (feat == 12 ? 1.f : 0.f)) : 0.f;
                __hip_bfloat162 h = __float22bfloat162_rn(make_float2(f0, f1));
                __builtin_memcpy(&w[d], &h, 4);
            }
            fpk[((size_t)side * T + t) * 64 + ln] = make_int4(w[0], w[1], w[2], w[3]);
        }
    }
}

// ---------------------------------------------------------------------------
// Kernel 1: partial scans. Block = 128 thr = 2 waves; each wave owns 64 queries.
// Loads are issued adjacent to use (R5 structure — hoisting caused scratch
// spill in R6: FETCH/WRITE ~0.6 GB each). Packed-fp32 argmin at half scale
// (bit-identical ordering to ref) + packed RBF distances; 8 MFMAs/tile.
// ---------------------------------------------------------------------------
__global__ __launch_bounds__(128, 3) void pip_partial(
    const float* __restrict__ locs_l, const float* __restrict__ locs_r,
    const float4* __restrict__ pk1p,  const float4* __restrict__ pkp,
    const int4* __restrict__ fpk,
    float* __restrict__ part, int L, int T, int CT)
{
#pragma clang fp contract(off)   // plain mul/add unfused; fma only where written
    const int lane = threadIdx.x & 63;
    const int wv = threadIdx.x >> 6;
    const int qbase = blockIdx.x * 128 + wv * 64;
    const int lq = qbase + lane;          // this lane's argmin query (L % 128 == 0)

    // argmin query data (half-scale |q|^2)
    const float qlx = locs_l[3 * lq + 0];
    const float qly = locs_l[3 * lq + 1];
    const float qlz = locs_l[3 * lq + 2];
    const float qrx = locs_r[3 * lq + 0];
    const float qry = locs_r[3 * lq + 1];
    const float qrz = locs_r[3 * lq + 2];
    const float nqhL = 0.5f * ((qlx * qlx + qly * qly) + qlz * qlz);
    const float nqhR = 0.5f * ((qrx * qrx + qry * qry) + qrz * qrz);
    const v2f qlx2 = {qlx, qlx}, qly2 = {qly, qly}, qlz2 = {qlz, qlz};
    const v2f qrx2 = {qrx, qry}, qry2 = {qry, qry}, qrz2 = {qrz, qrz};
    // (typo guard: qrx2 must be {qrx,qrx})
    const v2f qrx2f = {qrx, qrx};

    // RBF fragment-role queries: q = qbase + 16*mt + (lane&15)
    float qmlx[4], qmly[4], qmlz[4], qmrx[4], qmry[4], qmrz[4];
#pragma unroll
    for (int mt = 0; mt < 4; ++mt) {
        const int qm = qbase + 16 * mt + (lane & 15);
        qmlx[mt] = locs_l[3 * qm + 0];
        qmly[mt] = locs_l[3 * qm + 1];
        qmlz[mt] = locs_l[3 * qm + 2];
        qmrx[mt] = locs_r[3 * qm + 0];
        qmry[mt] = locs_r[3 * qm + 1];
        qmrz[mt] = locs_r[3 * qm + 2];
    }

    v4f cL[4], cR[4];
#pragma unroll
    for (int mt = 0; mt < 4; ++mt) { cL[mt] = (v4f)0.f; cR[mt] = (v4f)0.f; }

    float bdL = 3.4e38f, bdR = 3.4e38f;
    unsigned biL = 0u, biR = 0u;

    const int t0 = blockIdx.y * CT;
    const int t1 = (t0 + CT < T) ? (t0 + CT) : T;

    for (int tg = t0; tg < t1; ++tg) {
        // ---- argmin over 16 packed pairs (uniform addresses -> scalar loads)
        const int prb = tg * 16;
#pragma unroll 4
        for (int j = 0; j < 16; ++j) {
            const float4 XY1 = pk1p[(size_t)(prb + j) * 4 + 0];
            const float4 ZH1 = pk1p[(size_t)(prb + j) * 4 + 1];
            const float4 XY2 = pk1p[(size_t)(prb + j) * 4 + 2];
            const float4 ZH2 = pk1p[(size_t)(prb + j) * 4 + 3];
            {   // left: d2/2 = (|q|^2/2 + |p|^2/2) - dot ; ordering == ref
                const v2f xx = {XY1.x, XY1.y}, yy = {XY1.z, XY1.w};
                const v2f zz = {ZH1.x, ZH1.y}, hh = {ZH1.z, ZH1.w};
                const v2f dot = __builtin_elementwise_fma(qlz2, zz,
                                  __builtin_elementwise_fma(qly2, yy, qlx2 * xx));
                const v2f d2 = (nqhL + hh) - dot;
                const bool c0 = d2.x < bdL;
                bdL = c0 ? d2.x : bdL;
                biL = c0 ? (unsigned)(2 * (prb + j)) : biL;
                const bool c1 = d2.y < bdL;
                bdL = c1 ? d2.y : bdL;
                biL = c1 ? (unsigned)(2 * (prb + j) + 1) : biL;
            }
            {   // right
                const v2f xx = {XY2.x, XY2.y}, yy = {XY2.z, XY2.w};
                const v2f zz = {ZH2.x, ZH2.y}, hh = {ZH2.z, ZH2.w};
                const v2f dot = __builtin_elementwise_fma(qrz2, zz,
                                  __builtin_elementwise_fma(qry2, yy, qrx2f * xx));
                const v2f d2 = (nqhR + hh) - dot;
                const bool c0 = d2.x < bdR;
                bdR = c0 ? d2.x : bdR;
                biR = c0 ? (unsigned)(2 * (prb + j)) : biR;
                const bool c1 = d2.y < bdR;
                bdR = c1 ? d2.y : bdR;
                biR = c1 ? (unsigned)(2 * (prb + j) + 1) : biR;
            }
        }

        // ---- RBF: loads adjacent to use; packed distances; w's in A-frag order
        union AF { int i[4]; v8s s; };
        AF af1[4], af2[4];
        const int pg0 = tg * 16 + ((lane >> 4) << 2);   // this lane's 4 point-pairs
#pragma unroll
        for (int dp = 0; dp < 4; ++dp) {
            const float4 F0 = pkp[(size_t)(pg0 + dp) * 3 + 0];
            const float4 F1 = pkp[(size_t)(pg0 + dp) * 3 + 1];
            const float4 F2 = pkp[(size_t)(pg0 + dp) * 3 + 2];
            const v2f x1 = {F0.x, F0.y}, y1 = {F0.z, F0.w};
            const v2f x2 = {F1.x, F1.y}, y2 = {F1.z, F1.w};
            const v2f z1 = {F2.x, F2.y}, z2 = {F2.z, F2.w};
#pragma unroll
            for (int mt = 0; mt < 4; ++mt) {
                {   // side 1 (left)
                    const v2f dx = qmlx[mt] - x1, dy = qmly[mt] - y1, dz = qmlz[mt] - z1;
                    const v2f d2v = __builtin_elementwise_fma(dx, dx,
                                      __builtin_elementwise_fma(dy, dy, dz * dz));
                    const float w0 = __builtin_amdgcn_exp2f(C2_ * __builtin_amdgcn_sqrtf(d2v.x));
                    const float w1 = __builtin_amdgcn_exp2f(C2_ * __builtin_amdgcn_sqrtf(d2v.y));
                    __hip_bfloat162 h = __float22bfloat162_rn(make_float2(w0, w1));
                    __builtin_memcpy(&af1[mt].i[dp], &h, 4);
                }
                {   // side 2 (right)
                    const v2f dx = qmrx[mt] - x2, dy = qmry[mt] - y2, dz = qmrz[mt] - z2;
                    const v2f d2v = __builtin_elementwise_fma(dx, dx,
                                      __builtin_elementwise_fma(dy, dy, dz * dz));
                    const float w0 = __builtin_amdgcn_exp2f(C2_ * __builtin_amdgcn_sqrtf(d2v.x));
                    const float w1 = __builtin_amdgcn_exp2f(C2_ * __builtin_amdgcn_sqrtf(d2v.y));
                    __hip_bfloat162 h = __float22bfloat162_rn(make_float2(w0, w1));
                    __builtin_memcpy(&af2[mt].i[dp], &h, 4);
                }
            }
        }

        // ---- B-fragments loaded just before the 8 MFMAs
        const v8s b1 = ((const v8s*)fpk)[(size_t)tg * 64 + lane];
        const v8s b2 = ((const v8s*)fpk)[((size_t)T + tg) * 64 + lane];
#pragma unroll
        for (int mt = 0; mt < 4; ++mt) {
            cL[mt] = __builtin_amdgcn_mfma_f32_16x16x32_bf16(af1[mt].s, b1, cL[mt], 0, 0, 0);
            cR[mt] = __builtin_amdgcn_mfma_f32_16x16x32_bf16(af2[mt].s, b2, cR[mt], 0, 0, 0);
        }
    }

    // ---- store partials
    float* pbase = part + (size_t)(blockIdx.y * NSLOT) * (size_t)L;
    const int feat = lane & 15;
    if (feat < 13) {
        // C/D layout: col(=feat)=lane&15, row(=q within 16-tile)=(lane>>4)*4+reg
#pragma unroll
        for (int mt = 0; mt < 4; ++mt)
#pragma unroll
            for (int r = 0; r < 4; ++r) {
                const int q = qbase + 16 * mt + ((lane >> 4) << 2) + r;
                pbase[(size_t)feat * L + q]        = cL[mt][r];
                pbase[(size_t)(13 + feat) * L + q] = cR[mt][r];
            }
    }
    unsigned* pu = (unsigned*)pbase;
    pu[(size_t)26 * L + lq] = __float_as_uint(bdL);   // d2h > 0 -> bit-ordered
    pu[(size_t)27 * L + lq] = biL;
    pu[(size_t)28 * L + lq] = __float_as_uint(bdR);
    pu[(size_t)29 * L + lq] = biR;
}

// ---------------------------------------------------------------------------
// Kernel 2: wide reduction of SC chunks -> 1. blockIdx.y = task:
// 0..25 float-sum slots, 26 -> u64-min of (26,27), 27 -> u64-min of (28,29).
// ---------------------------------------------------------------------------
__global__ __launch_bounds__(BLK) void pip_sum(
    const float* __restrict__ part, float* __restrict__ red, int L, int SC)
{
    const int l = blockIdx.x * BLK + threadIdx.x;
    const int t = blockIdx.y;
    if (l >= L) return;
    if (t < 26) {
        float acc = 0.f;
        for (int s = 0; s < SC; ++s)
            acc += part[((size_t)s * NSLOT + t) * (size_t)L + (size_t)l];
        red[(size_t)t * L + (size_t)l] = acc;
    } else {
        const int base = (t == 26) ? 26 : 28;
        unsigned long long key = ~0ull;
        for (int s = 0; s < SC; ++s) {
            const unsigned* pu = (const unsigned*)(part + (size_t)(s * NSLOT) * (size_t)L);
            const unsigned d = pu[(size_t)base * L + (size_t)l];
            const unsigned i = pu[(size_t)(base + 1) * L + (size_t)l];
            const unsigned long long c = ((unsigned long long)d << 32) | (unsigned long long)i;
            key = c < key ? c : key;
        }
        unsigned* ru = (unsigned*)red;
        ru[(size_t)base * L + (size_t)l] = (unsigned)(key >> 32);
        ru[(size_t)(base + 1) * L + (size_t)l] = (unsigned)key;
    }
}

__device__ __forceinline__ float tanh_pos(float x) {
    const float t = __expf(-2.f * x);
    return (1.f - t) / (1.f + t);
}

// ---------------------------------------------------------------------------
// Kernel 3: gather nearest-node feats + 50->50->1 MLP. Thread = one query l.
// ---------------------------------------------------------------------------
__global__ __launch_bounds__(BLK) void pip_final(
    const float* __restrict__ red,
    const float* __restrict__ g1_x, const float* __restrict__ g2_x,
    const float* __restrict__ W1, const float* __restrict__ b1,
    const float* __restrict__ W2, const float* __restrict__ b2,
    float* __restrict__ out, int L)
{
#pragma clang fp contract(off)
    const int l = blockIdx.x * BLK + threadIdx.x;
    if (l >= L) return;

    const unsigned* ru = (const unsigned*)red;
    const unsigned idxL = ru[(size_t)27 * L + (size_t)l];
    const unsigned idxR = ru[(size_t)29 * L + (size_t)l];
    const float normL = red[(size_t)12 * L + (size_t)l] + EPS_;
    const float normR = red[(size_t)25 * L + (size_t)l] + EPS_;

    float x[50];
    {
        const float4* f = (const float4*)(g1_x + (size_t)idxL * DG);
        const float4 f0 = f[0], f1 = f[1], f2 = f[2];
        x[0] = f0.x; x[1] = f0.y; x[2]  = f0.z; x[3]  = f0.w;
        x[4] = f1.x; x[5] = f1.y; x[6]  = f1.z; x[7]  = f1.w;
        x[8] = f2.x; x[9] = f2.y; x[10] = f2.z; x[11] = f2.w;
    }
#pragma unroll
    for (int k = 0; k < DG; ++k) x[12 + k] = red[(size_t)k * L + (size_t)l] / normL;
    x[24] = tanh_pos(normL);
    {
        const float4* f = (const float4*)(g2_x + (size_t)idxR * DG);
        const float4 f0 = f[0], f1 = f[1], f2 = f[2];
        x[25] = f0.x; x[26] = f0.y; x[27] = f0.z; x[28] = f0.w;
        x[29] = f1.x; x[30] = f1.y; x[31] = f1.z; x[32] = f1.w;
        x[33] = f2.x; x[34] = f2.y; x[35] = f2.z; x[36] = f2.w;
    }
#pragma unroll
    for (int k = 0; k < DG; ++k) x[37 + k] = red[(size_t)(13 + k) * L + (size_t)l] / normR;
    x[49] = tanh_pos(normR);

    float h[50];
#pragma unroll
    for (int j = 0; j < 50; ++j) h[j] = b1[j];
#pragma unroll
    for (int k = 0; k < 50; ++k) {
        const float xk = x[k];
#pragma unroll
        for (int j = 0; j < 50; ++j) h[j] = fmaf(xk, W1[k * 50 + j], h[j]);
    }
    float o = b2[0];
#pragma unroll
    for (int j = 0; j < 50; ++j) o = fmaf(fmaxf(h[j], 0.f), W2[j], o);
    out[l] = o;
}

// ---------------------------------------------------------------------------
extern "C" void kernel_launch(void* const* d_in, const int* in_sizes, int n_in,
                              void* d_out, int out_size, void* d_ws, size_t ws_size,
                              hipStream_t stream) {
    const float* locs_l = (const float*)d_in[0];
    const float* locs_r = (const float*)d_in[1];
    const float* g1_pos = (const float*)d_in[2];
    const float* g1_x   = (const float*)d_in[3];
    const float* g2_pos = (const float*)d_in[4];
    const float* g2_x   = (const float*)d_in[5];
    const float* s1_v   = (const float*)d_in[6];
    const float* s1_x   = (const float*)d_in[7];
    const float* s2_v   = (const float*)d_in[8];
    const float* s2_x   = (const float*)d_in[9];
    const float* W1     = (const float*)d_in[10];
    const float* b1     = (const float*)d_in[11];
    const float* W2     = (const float*)d_in[12];
    const float* b2     = (const float*)d_in[13];
    float* out = (float*)d_out;
    float* ws  = (float*)d_ws;

    const int L = in_sizes[0] / 3;   // 4096
    const int N = in_sizes[2] / 3;   // 40000
    const int T = (N + 31) / 32;     // 32-point tiles (1250, exact)

    // ws layout (floats): [pk1p: 256T][pkp: 192T][fpk: 512T][part: SC*30*L][red: 30*L]
    const size_t o_pkp  = (size_t)256 * T;
    const size_t o_fpk  = (size_t)448 * T;
    const size_t o_part = (size_t)960 * T;

    // chunk size in tiles; SC chunks -> grid.y ~63 (grid 32x63 = 2016 blocks).
    int CT = 20;
    int SC = (T + CT - 1) / CT;
    while (CT < T) {
        const size_t need = (o_part + (size_t)(SC + 1) * NSLOT * (size_t)L) * sizeof(float);
        if (need <= ws_size) break;
        CT *= 2;
        SC = (T + CT - 1) / CT;
    }

    float4* pk1p = (float4*)ws;
    float4* pkp  = (float4*)(ws + o_pkp);
    int4*   fpk  = (int4*)(ws + o_fpk);
    float*  part = ws + o_part;
    float*  red  = part + (size_t)SC * NSLOT * (size_t)L;

    const int ptasks = 48 * T + 128 * T;    // 3P + 128T, P = 16T
    pip_pack<<<dim3((ptasks + BLK - 1) / BLK), dim3(BLK), 0, stream>>>(
        g1_pos, g2_pos, s1_v, s1_x, s2_v, s2_x, pk1p, pkp, fpk, N, T);

    pip_partial<<<dim3(L / 128, SC), dim3(128), 0, stream>>>(
        locs_l, locs_r, pk1p, pkp, fpk, part, L, T, CT);

    const int lblocks = (L + BLK - 1) / BLK;
    pip_sum<<<dim3(lblocks, 28), dim3(BLK), 0, stream>>>(part, red, L, SC);

    pip_final<<<dim3(lblocks), dim3(BLK), 0, stream>>>(
        red, g1_x, g2_x, W1, b1, W2, b2, out, L);
}

// Round 8
// 371.757 us; speedup vs baseline: 1.4951x; 1.0218x over previous
//
#include <hip/hip_runtime.h>
#include <hip/hip_bf16.h>
#include <cstdint>
#include <cstddef>

#define BLK 256     // pack/init/final block size
#define DG 12

static constexpr float EPS_ = 0.01f;
// exp(-d/sigma) == exp2(c2 * d), c2 = -1/(sigma*ln2), sigma = 2.5
static constexpr float C2_ = -0.57707801635558534f;

typedef __attribute__((ext_vector_type(2))) float v2f;   // packed fp32 (VOP3P)
typedef __attribute__((ext_vector_type(8))) short v8s;   // 8 bf16 (MFMA A/B frag)
typedef __attribute__((ext_vector_type(4))) float v4f;   // MFMA C/D frag

// ---------------------------------------------------------------------------
// Kernel 0: pack into pair-interleaved streams (P = point pairs = 16T).
//  pk1p[(pair*2+side)] -> 2 float4: {x0,x1,y0,y1}, {z0,z1,h0,h1}, h = |p|^2/2
//  pkp[pair] -> 3 float4: {s1:x0,x1,y0,y1}, {s2:x0,x1,y0,y1}, {s1:z0,z1, s2:z0,z1}
//  fpk[side][tile][lane] -> int4 B-fragment of F = [s_x(12), 1.0] in bf16
// Pads (n>=N): pos 1e9 (argmin never wins; w==0), F=0.
// ---------------------------------------------------------------------------
__global__ __launch_bounds__(BLK) void pip_pack(
    const float* __restrict__ g1_pos, const float* __restrict__ g2_pos,
    const float* __restrict__ s1_v,   const float* __restrict__ s1_x,
    const float* __restrict__ s2_v,   const float* __restrict__ s2_x,
    float4* __restrict__ pk1p, float4* __restrict__ pkp, int4* __restrict__ fpk,
    int N, int T)
{
#pragma clang fp contract(off)
    const int P = T * 16;
    const int tid = blockIdx.x * BLK + threadIdx.x;
    if (tid < 2 * P) {                         // pk1p
        const int pr = tid >> 1;
        const float* src = (tid & 1) ? g2_pos : g1_pos;
        const int n0 = 2 * pr, n1 = 2 * pr + 1;
        float x0 = 1e9f, y0 = 1e9f, z0 = 1e9f, h0 = 1.5e18f;
        float x1 = 1e9f, y1 = 1e9f, z1 = 1e9f, h1 = 1.5e18f;
        if (n0 < N) {
            x0 = src[3 * n0]; y0 = src[3 * n0 + 1]; z0 = src[3 * n0 + 2];
            h0 = 0.5f * ((x0 * x0 + y0 * y0) + z0 * z0);   // exact half of ref |p|^2
        }
        if (n1 < N) {
            x1 = src[3 * n1]; y1 = src[3 * n1 + 1]; z1 = src[3 * n1 + 2];
            h1 = 0.5f * ((x1 * x1 + y1 * y1) + z1 * z1);
        }
        pk1p[(size_t)tid * 2 + 0] = make_float4(x0, x1, y0, y1);
        pk1p[(size_t)tid * 2 + 1] = make_float4(z0, z1, h0, h1);
    } else if (tid < 3 * P) {                  // pkp
        const int pr = tid - 2 * P;
        const int n0 = 2 * pr, n1 = 2 * pr + 1;
        float a0 = 1e9f, b0 = 1e9f, c0 = 1e9f, a1 = 1e9f, b1 = 1e9f, c1 = 1e9f;
        float d0 = 1e9f, e0 = 1e9f, f0 = 1e9f, d1 = 1e9f, e1 = 1e9f, f1 = 1e9f;
        if (n0 < N) { a0 = s1_v[3 * n0]; b0 = s1_v[3 * n0 + 1]; c0 = s1_v[3 * n0 + 2];
                      d0 = s2_v[3 * n0]; e0 = s2_v[3 * n0 + 1]; f0 = s2_v[3 * n0 + 2]; }
        if (n1 < N) { a1 = s1_v[3 * n1]; b1 = s1_v[3 * n1 + 1]; c1 = s1_v[3 * n1 + 2];
                      d1 = s2_v[3 * n1]; e1 = s2_v[3 * n1 + 1]; f1 = s2_v[3 * n1 + 2]; }
        pkp[(size_t)pr * 3 + 0] = make_float4(a0, a1, b0, b1);
        pkp[(size_t)pr * 3 + 1] = make_float4(d0, d1, e0, e1);
        pkp[(size_t)pr * 3 + 2] = make_float4(c0, c1, f0, f1);
    } else {                                   // fpk B-fragments
        const int u = tid - 3 * P;
        if (u < 128 * T) {
            const int side = u / (64 * T);
            const int r = u - side * 64 * T;
            const int t = r >> 6;
            const int ln = r & 63;
            const float* X = side ? s2_x : s1_x;
            const int nb = 32 * t + ((ln >> 4) << 3);
            const int feat = ln & 15;
            int w[4];
#pragma unroll
            for (int d = 0; d < 4; ++d) {
                const int n0 = nb + 2 * d, n1 = nb + 2 * d + 1;
                const float f0 = (n0 < N) ? (feat < 12 ? X[(size_t)n0 * DG + feat] : (feat == 12 ? 1.f : 0.f)) : 0.f;
                const float f1 = (n1 < N) ? (feat < 12 ? X[(size_t)n1 * DG + feat] : (feat == 12 ? 1.f : 0.f)) : 0.f;
                __hip_bfloat162 h = __float22bfloat162_rn(make_float2(f0, f1));
                __builtin_memcpy(&w[d], &h, 4);
            }
            fpk[((size_t)side * T + t) * 64 + ln] = make_int4(w[0], w[1], w[2], w[3]);
        }
    }
}

// ---------------------------------------------------------------------------
// Kernel 0b: init accumulators. red: 26*L float sums = 0; keys: 2*L u64 = ~0.
// (d_ws is poisoned 0xAA; 0 would be wrong for the min-keys.)
// ---------------------------------------------------------------------------
__global__ __launch_bounds__(BLK) void pip_init(
    float* __restrict__ red, unsigned long long* __restrict__ keys, int L)
{
    const int i = blockIdx.x * BLK + threadIdx.x;
    if (i < 26 * L) red[i] = 0.f;
    else if (i < 28 * L) keys[i - 26 * L] = ~0ull;
}

// ---------------------------------------------------------------------------
// Kernel 1: partial scans, side-split. Block = 128 thr = 2 waves, handles ONE
// side (blockIdx.z): halves register state vs the fused version -> more waves
// resident. Results go straight into red/keys via device atomics (no partials
// array, no reduce kernel). Argmin: packed fp32 at half scale — bit-identical
// ordering to the reference's |q|^2+|p|^2-2q.p fp32 formula. Loads stay
// adjacent to use (R6 lesson: hoisting -> scratch spill).
// ---------------------------------------------------------------------------
__global__ __launch_bounds__(128, 4) void pip_partial(
    const float* __restrict__ locs_l, const float* __restrict__ locs_r,
    const float4* __restrict__ pk1p,  const float4* __restrict__ pkp,
    const int4* __restrict__ fpk,
    float* __restrict__ red, unsigned long long* __restrict__ keys,
    int L, int T, int CT)
{
#pragma clang fp contract(off)   // plain mul/add unfused; fma only where written
    const int lane = threadIdx.x & 63;
    const int wv = threadIdx.x >> 6;
    const int side = blockIdx.z;
    const int qbase = blockIdx.x * 128 + wv * 64;
    const int lq = qbase + lane;          // this lane's argmin query (L % 128 == 0)

    const float* __restrict__ locs = side ? locs_r : locs_l;

    // argmin query data (half-scale |q|^2)
    const float qx = locs[3 * lq + 0];
    const float qy = locs[3 * lq + 1];
    const float qz = locs[3 * lq + 2];
    const float nqh = 0.5f * ((qx * qx + qy * qy) + qz * qz);
    const v2f qx2 = {qx, qx}, qy2 = {qy, qy}, qz2 = {qz, qz};

    // RBF fragment-role queries: q = qbase + 16*mt + (lane&15)
    float qmx[4], qmy[4], qmz[4];
#pragma unroll
    for (int mt = 0; mt < 4; ++mt) {
        const int qm = qbase + 16 * mt + (lane & 15);
        qmx[mt] = locs[3 * qm + 0];
        qmy[mt] = locs[3 * qm + 1];
        qmz[mt] = locs[3 * qm + 2];
    }

    v4f cC[4];
#pragma unroll
    for (int mt = 0; mt < 4; ++mt) cC[mt] = (v4f)0.f;

    float bd = 3.4e38f;
    unsigned bi = 0u;

    const int t0 = blockIdx.y * CT;
    const int t1 = (t0 + CT < T) ? (t0 + CT) : T;

    for (int tg = t0; tg < t1; ++tg) {
        // ---- argmin over 16 packed pairs (uniform addresses -> scalar loads)
        const int prb = tg * 16;
#pragma unroll 4
        for (int j = 0; j < 16; ++j) {
            const float4 XY = pk1p[(size_t)((prb + j) * 2 + side) * 2 + 0];
            const float4 ZH = pk1p[(size_t)((prb + j) * 2 + side) * 2 + 1];
            const v2f xx = {XY.x, XY.y}, yy = {XY.z, XY.w};
            const v2f zz = {ZH.x, ZH.y}, hh = {ZH.z, ZH.w};
            const v2f dot = __builtin_elementwise_fma(qz2, zz,
                              __builtin_elementwise_fma(qy2, yy, qx2 * xx));
            const v2f d2 = (nqh + hh) - dot;   // d2/2; ordering == ref (RN scale-comm)
            const bool c0 = d2.x < bd;
            bd = c0 ? d2.x : bd;
            bi = c0 ? (unsigned)(2 * (prb + j)) : bi;
            const bool c1 = d2.y < bd;
            bd = c1 ? d2.y : bd;
            bi = c1 ? (unsigned)(2 * (prb + j) + 1) : bi;
        }

        // ---- RBF: loads adjacent to use; packed distances; w's in A-frag order
        union AF { int i[4]; v8s s; };
        AF af[4];
        const int pg0 = tg * 16 + ((lane >> 4) << 2);   // this lane's 4 point-pairs
#pragma unroll
        for (int dp = 0; dp < 4; ++dp) {
            const float4 FXY = pkp[(size_t)(pg0 + dp) * 3 + side];
            const float4 FZ  = pkp[(size_t)(pg0 + dp) * 3 + 2];
            const v2f px = {FXY.x, FXY.y}, py = {FXY.z, FXY.w};
            const v2f pz = side ? (v2f){FZ.z, FZ.w} : (v2f){FZ.x, FZ.y};
#pragma unroll
            for (int mt = 0; mt < 4; ++mt) {
                const v2f dx = qmx[mt] - px, dy = qmy[mt] - py, dz = qmz[mt] - pz;
                const v2f d2v = __builtin_elementwise_fma(dx, dx,
                                  __builtin_elementwise_fma(dy, dy, dz * dz));
                const float w0 = __builtin_amdgcn_exp2f(C2_ * __builtin_amdgcn_sqrtf(d2v.x));
                const float w1 = __builtin_amdgcn_exp2f(C2_ * __builtin_amdgcn_sqrtf(d2v.y));
                __hip_bfloat162 h = __float22bfloat162_rn(make_float2(w0, w1));
                __builtin_memcpy(&af[mt].i[dp], &h, 4);
            }
        }

        // ---- B-fragment + 4 MFMAs
        const v8s b = ((const v8s*)fpk)[((size_t)side * T + tg) * 64 + lane];
#pragma unroll
        for (int mt = 0; mt < 4; ++mt)
            cC[mt] = __builtin_amdgcn_mfma_f32_16x16x32_bf16(af[mt].s, b, cC[mt], 0, 0, 0);
    }

    // ---- accumulate into red/keys with device atomics
    const int feat = lane & 15;
    if (feat < 13) {
        const int slot = side * 13 + feat;
        // C/D layout: col(=feat)=lane&15, row(=q within 16-tile)=(lane>>4)*4+reg
#pragma unroll
        for (int mt = 0; mt < 4; ++mt)
#pragma unroll
            for (int r = 0; r < 4; ++r) {
                const int q = qbase + 16 * mt + ((lane >> 4) << 2) + r;
                atomicAdd(&red[(size_t)slot * L + q], cC[mt][r]);
            }
    }
    const unsigned long long key =
        ((unsigned long long)__float_as_uint(bd) << 32) | (unsigned long long)bi;
    atomicMin(&keys[(size_t)side * L + lq], key);   // d2h > 0 -> bit-ordered
}

__device__ __forceinline__ float tanh_pos(float x) {
    const float t = __expf(-2.f * x);
    return (1.f - t) / (1.f + t);
}

// ---------------------------------------------------------------------------
// Kernel 2: gather nearest-node feats + 50->50->1 MLP. Thread = one query l.
// ---------------------------------------------------------------------------
__global__ __launch_bounds__(BLK) void pip_final(
    const float* __restrict__ red, const unsigned long long* __restrict__ keys,
    const float* __restrict__ g1_x, const float* __restrict__ g2_x,
    const float* __restrict__ W1, const float* __restrict__ b1,
    const float* __restrict__ W2, const float* __restrict__ b2,
    float* __restrict__ out, int L)
{
#pragma clang fp contract(off)
    const int l = blockIdx.x * BLK + threadIdx.x;
    if (l >= L) return;

    const unsigned idxL = (unsigned)(keys[l] & 0xffffffffull);
    const unsigned idxR = (unsigned)(keys[(size_t)L + l] & 0xffffffffull);
    const float normL = red[(size_t)12 * L + (size_t)l] + EPS_;
    const float normR = red[(size_t)25 * L + (size_t)l] + EPS_;

    float x[50];
    {
        const float4* f = (const float4*)(g1_x + (size_t)idxL * DG);
        const float4 f0 = f[0], f1 = f[1], f2 = f[2];
        x[0] = f0.x; x[1] = f0.y; x[2]  = f0.z; x[3]  = f0.w;
        x[4] = f1.x; x[5] = f1.y; x[6]  = f1.z; x[7]  = f1.w;
        x[8] = f2.x; x[9] = f2.y; x[10] = f2.z; x[11] = f2.w;
    }
#pragma unroll
    for (int k = 0; k < DG; ++k) x[12 + k] = red[(size_t)k * L + (size_t)l] / normL;
    x[24] = tanh_pos(normL);
    {
        const float4* f = (const float4*)(g2_x + (size_t)idxR * DG);
        const float4 f0 = f[0], f1 = f[1], f2 = f[2];
        x[25] = f0.x; x[26] = f0.y; x[27] = f0.z; x[28] = f0.w;
        x[29] = f1.x; x[30] = f1.y; x[31] = f1.z; x[32] = f1.w;
        x[33] = f2.x; x[34] = f2.y; x[35] = f2.z; x[36] = f2.w;
    }
#pragma unroll
    for (int k = 0; k < DG; ++k) x[37 + k] = red[(size_t)(13 + k) * L + (size_t)l] / normR;
    x[49] = tanh_pos(normR);

    float h[50];
#pragma unroll
    for (int j = 0; j < 50; ++j) h[j] = b1[j];
#pragma unroll
    for (int k = 0; k < 50; ++k) {
        const float xk = x[k];
#pragma unroll
        for (int j = 0; j < 50; ++j) h[j] = fmaf(xk, W1[k * 50 + j], h[j]);
    }
    float o = b2[0];
#pragma unroll
    for (int j = 0; j < 50; ++j) o = fmaf(fmaxf(h[j], 0.f), W2[j], o);
    out[l] = o;
}

// ---------------------------------------------------------------------------
extern "C" void kernel_launch(void* const* d_in, const int* in_sizes, int n_in,
                              void* d_out, int out_size, void* d_ws, size_t ws_size,
                              hipStream_t stream) {
    const float* locs_l = (const float*)d_in[0];
    const float* locs_r = (const float*)d_in[1];
    const float* g1_pos = (const float*)d_in[2];
    const float* g1_x   = (const float*)d_in[3];
    const float* g2_pos = (const float*)d_in[4];
    const float* g2_x   = (const float*)d_in[5];
    const float* s1_v   = (const float*)d_in[6];
    const float* s1_x   = (const float*)d_in[7];
    const float* s2_v   = (const float*)d_in[8];
    const float* s2_x   = (const float*)d_in[9];
    const float* W1     = (const float*)d_in[10];
    const float* b1     = (const float*)d_in[11];
    const float* W2     = (const float*)d_in[12];
    const float* b2     = (const float*)d_in[13];
    float* out = (float*)d_out;
    float* ws  = (float*)d_ws;

    const int L = in_sizes[0] / 3;   // 4096
    const int N = in_sizes[2] / 3;   // 40000
    const int T = (N + 31) / 32;     // 32-point tiles (1250, exact)

    // ws layout (floats): [pk1p: 256T][pkp: 192T][fpk: 512T][red: 26L][keys: 2L u64]
    const size_t o_pkp = (size_t)256 * T;
    const size_t o_fpk = (size_t)448 * T;
    const size_t o_red = (size_t)960 * T;

    const int CT = 10;                       // tiles per chunk
    const int SC = (T + CT - 1) / CT;        // 125 chunks -> grid 32 x 125 x 2

    float4* pk1p = (float4*)ws;
    float4* pkp  = (float4*)(ws + o_pkp);
    int4*   fpk  = (int4*)(ws + o_fpk);
    float*  red  = ws + o_red;
    unsigned long long* keys = (unsigned long long*)(red + (size_t)26 * L);

    const int ptasks = 176 * T;              // 3P + 128T, P = 16T
    pip_pack<<<dim3((ptasks + BLK - 1) / BLK), dim3(BLK), 0, stream>>>(
        g1_pos, g2_pos, s1_v, s1_x, s2_v, s2_x, pk1p, pkp, fpk, N, T);

    pip_init<<<dim3((28 * L + BLK - 1) / BLK), dim3(BLK), 0, stream>>>(red, keys, L);

    pip_partial<<<dim3(L / 128, SC, 2), dim3(128), 0, stream>>>(
        locs_l, locs_r, pk1p, pkp, fpk, red, keys, L, T, CT);

    pip_final<<<dim3((L + BLK - 1) / BLK), dim3(BLK), 0, stream>>>(
        red, keys, g1_x, g2_x, W1, b1, W2, b2, out, L);
}

// Round 9
// 303.666 us; speedup vs baseline: 1.8303x; 1.2242x over previous
//
#include <hip/hip_runtime.h>
#include <hip/hip_bf16.h>
#include <cstdint>
#include <cstddef>

#define BLK 256     // pack/final block size
#define DG 12

static constexpr float EPS_ = 0.01f;
// exp(-d/sigma) = exp2(C2*d), C2 = -1/(sigma*ln2), sigma=2.5; C2SQ = C2^2
static constexpr float C2SQ_ = 0.333019070232236f;

typedef __attribute__((ext_vector_type(2))) float v2f;   // packed fp32 (VOP3P)
typedef __attribute__((ext_vector_type(8))) short v8s;   // 8 bf16 (MFMA A/B frag)
typedef __attribute__((ext_vector_type(4))) float v4f;   // MFMA C/D frag

// ---------------------------------------------------------------------------
// Kernel 0: pack (side-major streams) + init accumulators. P = point pairs.
//  pk1s[side*P+pr] -> {x0,x1,y0,y1},{z0,z1,h0,h1}  h=|p|^2/2  (argmin, uniform)
//  pkps[side*P+pr] -> {x0,x1,y0,y1},{z0,z1,h0,h1}  h=|p|^2    (RBF dot-form)
//  fpk[side][tile][lane] -> int4 B-frag of F=[s_x(12),1.0] bf16
//  red[26L]=0, keys[2L]=~0 (ws is 0xAA-poisoned; min-keys need ~0).
// Pads (n>=N): pos 1e9, h huge (argmin never wins; w==0), F=0.
// ---------------------------------------------------------------------------
__global__ __launch_bounds__(BLK) void pip_pack(
    const float* __restrict__ g1_pos, const float* __restrict__ g2_pos,
    const float* __restrict__ s1_v,   const float* __restrict__ s1_x,
    const float* __restrict__ s2_v,   const float* __restrict__ s2_x,
    float4* __restrict__ pk1s, float4* __restrict__ pkps, int4* __restrict__ fpk,
    float* __restrict__ red, unsigned long long* __restrict__ keys,
    int N, int T, int L)
{
#pragma clang fp contract(off)
    const int P = T * 16;
    const int tid = blockIdx.x * BLK + threadIdx.x;

    // ---- init accumulators (merged to save a launch)
    if (tid < 26 * L) red[tid] = 0.f;
    else if (tid < 28 * L) keys[tid - 26 * L] = ~0ull;

    // ---- pack tasks
    if (tid < 2 * P) {                         // pk1s: tid = side*P + pr
        const int side = tid / P;
        const int pr = tid - side * P;
        const float* src = side ? g2_pos : g1_pos;
        const int n0 = 2 * pr, n1 = 2 * pr + 1;
        float x0 = 1e9f, y0 = 1e9f, z0 = 1e9f, h0 = 1.5e18f;
        float x1 = 1e9f, y1 = 1e9f, z1 = 1e9f, h1 = 1.5e18f;
        if (n0 < N) {
            x0 = src[3 * n0]; y0 = src[3 * n0 + 1]; z0 = src[3 * n0 + 2];
            h0 = 0.5f * ((x0 * x0 + y0 * y0) + z0 * z0);   // exact half of ref |p|^2
        }
        if (n1 < N) {
            x1 = src[3 * n1]; y1 = src[3 * n1 + 1]; z1 = src[3 * n1 + 2];
            h1 = 0.5f * ((x1 * x1 + y1 * y1) + z1 * z1);
        }
        pk1s[(size_t)tid * 2 + 0] = make_float4(x0, x1, y0, y1);
        pk1s[(size_t)tid * 2 + 1] = make_float4(z0, z1, h0, h1);
    } else if (tid < 4 * P) {                  // pkps: u = side*P + pr
        const int u = tid - 2 * P;
        const int side = u / P;
        const int pr = u - side * P;
        const float* src = side ? s2_v : s1_v;
        const int n0 = 2 * pr, n1 = 2 * pr + 1;
        float x0 = 1e9f, y0 = 1e9f, z0 = 1e9f, h0 = 3e18f;
        float x1 = 1e9f, y1 = 1e9f, z1 = 1e9f, h1 = 3e18f;
        if (n0 < N) {
            x0 = src[3 * n0]; y0 = src[3 * n0 + 1]; z0 = src[3 * n0 + 2];
            h0 = (x0 * x0 + y0 * y0) + z0 * z0;            // full |p|^2 (RBF dot-form)
        }
        if (n1 < N) {
            x1 = src[3 * n1]; y1 = src[3 * n1 + 1]; z1 = src[3 * n1 + 2];
            h1 = (x1 * x1 + y1 * y1) + z1 * z1;
        }
        pkps[(size_t)u * 2 + 0] = make_float4(x0, x1, y0, y1);
        pkps[(size_t)u * 2 + 1] = make_float4(z0, z1, h0, h1);
    } else {                                   // fpk B-fragments
        const int u = tid - 4 * P;
        if (u < 128 * T) {
            const int side = u / (64 * T);
            const int r = u - side * 64 * T;
            const int t = r >> 6;
            const int ln = r & 63;
            const float* X = side ? s2_x : s1_x;
            const int nb = 32 * t + ((ln >> 4) << 3);
            const int feat = ln & 15;
            int w[4];
#pragma unroll
            for (int d = 0; d < 4; ++d) {
                const int n0 = nb + 2 * d, n1 = nb + 2 * d + 1;
                const float f0 = (n0 < N) ? (feat < 12 ? X[(size_t)n0 * DG + feat] : (feat == 12 ? 1.f : 0.f)) : 0.f;
                const float f1 = (n1 < N) ? (feat < 12 ? X[(size_t)n1 * DG + feat] : (feat == 12 ? 1.f : 0.f)) : 0.f;
                __hip_bfloat162 h = __float22bfloat162_rn(make_float2(f0, f1));
                __builtin_memcpy(&w[d], &h, 4);
            }
            fpk[((size_t)side * T + t) * 64 + ln] = make_int4(w[0], w[1], w[2], w[3]);
        }
    }
}

// ---------------------------------------------------------------------------
// Kernel 1: partial scans, side-split, dp-interleaved. Block = 128 thr = 2
// waves; one side per block (blockIdx.z). Per 4-pair group (dp): issue the
// group's RBF vector loads, run 4 argmin iterations (uniform scalar loads)
// to hide their latency, then consume — live range ~12 VGPRs (no R6 spill).
// Argmin: packed fp32 half-scale — bit-identical ordering to the reference's
// |q|^2+|p|^2-2q.p fp32 formula. RBF: dot-form d2 (clamped) + C2^2 fold:
// w = exp2(-sqrt(C2SQ*d2)); error ~1e-5 rel, invisible under bf16.
// Results accumulate via device atomics into red/keys.
// ---------------------------------------------------------------------------
__global__ __launch_bounds__(128, 4) void pip_partial(
    const float* __restrict__ locs_l, const float* __restrict__ locs_r,
    const float4* __restrict__ pk1s,  const float4* __restrict__ pkps,
    const int4* __restrict__ fpk,
    float* __restrict__ red, unsigned long long* __restrict__ keys,
    int L, int T, int CT, int P)
{
#pragma clang fp contract(off)   // plain mul/add unfused; fma only where written
    const int lane = threadIdx.x & 63;
    const int wv = threadIdx.x >> 6;
    const int side = blockIdx.z;
    const int qbase = blockIdx.x * 128 + wv * 64;
    const int lq = qbase + lane;          // this lane's argmin query (L % 128 == 0)

    const float* __restrict__ locs = side ? locs_r : locs_l;

    // argmin query data (half-scale |q|^2)
    const float qx = locs[3 * lq + 0];
    const float qy = locs[3 * lq + 1];
    const float qz = locs[3 * lq + 2];
    const float nqh = 0.5f * ((qx * qx + qy * qy) + qz * qz);
    const v2f qx2 = {qx, qx}, qy2 = {qy, qy}, qz2 = {qz, qz};

    // RBF fragment-role queries: q = qbase + 16*mt + (lane&15); dot-form consts
    float nq2[4], m2x[4], m2y[4], m2z[4];
#pragma unroll
    for (int mt = 0; mt < 4; ++mt) {
        const int qm = qbase + 16 * mt + (lane & 15);
        const float a = locs[3 * qm + 0];
        const float b = locs[3 * qm + 1];
        const float c = locs[3 * qm + 2];
        nq2[mt] = (a * a + b * b) + c * c;
        m2x[mt] = -2.0f * a; m2y[mt] = -2.0f * b; m2z[mt] = -2.0f * c;
    }

    v4f cC[4];
#pragma unroll
    for (int mt = 0; mt < 4; ++mt) cC[mt] = (v4f)0.f;

    float bd = 3.4e38f;
    unsigned bi = 0u;

    const float4* __restrict__ pk1b = pk1s + (size_t)side * P * 2;
    const float4* __restrict__ pkpb = pkps + (size_t)side * P * 2;

    const int t0 = blockIdx.y * CT;
    const int t1 = (t0 + CT < T) ? (t0 + CT) : T;

    for (int tg = t0; tg < t1; ++tg) {
        const v8s b = ((const v8s*)fpk)[((size_t)side * T + tg) * 64 + lane];  // used at tile end
        union AF { int i[4]; v8s s; };
        AF af[4];
        const int prb = tg * 16;
        const int pg0 = prb + ((lane >> 4) << 2);   // this lane's 4 point-pairs

#pragma unroll
        for (int dp = 0; dp < 4; ++dp) {
            // ---- issue this group's RBF loads (latency hidden by argmin below)
            const float4 FXY = pkpb[(size_t)(pg0 + dp) * 2 + 0];
            const float4 FZH = pkpb[(size_t)(pg0 + dp) * 2 + 1];

            // ---- argmin: 4 packed-pair iterations (uniform -> scalar loads)
#pragma unroll
            for (int jj = 0; jj < 4; ++jj) {
                const int j = 4 * dp + jj;
                const float4 XY = pk1b[(size_t)(prb + j) * 2 + 0];
                const float4 ZH = pk1b[(size_t)(prb + j) * 2 + 1];
                const v2f xx = {XY.x, XY.y}, yy = {XY.z, XY.w};
                const v2f zz = {ZH.x, ZH.y}, hh = {ZH.z, ZH.w};
                const v2f dot = __builtin_elementwise_fma(qz2, zz,
                                  __builtin_elementwise_fma(qy2, yy, qx2 * xx));
                const v2f d2 = (nqh + hh) - dot;   // d2/2; ordering == ref
                const bool c0 = d2.x < bd;
                bd = c0 ? d2.x : bd;
                bi = c0 ? (unsigned)(2 * (prb + j)) : bi;
                const bool c1 = d2.y < bd;
                bd = c1 ? d2.y : bd;
                bi = c1 ? (unsigned)(2 * (prb + j) + 1) : bi;
            }

            // ---- RBF for this group: dot-form distance, folded transcendentals
            const v2f px = {FXY.x, FXY.y}, py = {FXY.z, FXY.w};
            const v2f pz = {FZH.x, FZH.y}, ph = {FZH.z, FZH.w};
#pragma unroll
            for (int mt = 0; mt < 4; ++mt) {
                const v2f mx = {m2x[mt], m2x[mt]};
                const v2f my = {m2y[mt], m2y[mt]};
                const v2f mz = {m2z[mt], m2z[mt]};
                const v2f s  = nq2[mt] + ph;
                const v2f d2v = __builtin_elementwise_fma(mz, pz,
                                  __builtin_elementwise_fma(my, py,
                                    __builtin_elementwise_fma(mx, px, s)));
                v2f t = C2SQ_ * d2v;
                t = __builtin_elementwise_max(t, (v2f)0.f);   // cancellation guard
                const float w0 = __builtin_amdgcn_exp2f(-__builtin_amdgcn_sqrtf(t.x));
                const float w1 = __builtin_amdgcn_exp2f(-__builtin_amdgcn_sqrtf(t.y));
                __hip_bfloat162 h = __float22bfloat162_rn(make_float2(w0, w1));
                __builtin_memcpy(&af[mt].i[dp], &h, 4);
            }
        }

        // ---- 4 MFMAs
#pragma unroll
        for (int mt = 0; mt < 4; ++mt)
            cC[mt] = __builtin_amdgcn_mfma_f32_16x16x32_bf16(af[mt].s, b, cC[mt], 0, 0, 0);
    }

    // ---- accumulate into red/keys with device atomics
    const int feat = lane & 15;
    if (feat < 13) {
        const int slot = side * 13 + feat;
        // C/D layout: col(=feat)=lane&15, row(=q within 16-tile)=(lane>>4)*4+reg
#pragma unroll
        for (int mt = 0; mt < 4; ++mt)
#pragma unroll
            for (int r = 0; r < 4; ++r) {
                const int q = qbase + 16 * mt + ((lane >> 4) << 2) + r;
                atomicAdd(&red[(size_t)slot * L + q], cC[mt][r]);
            }
    }
    const unsigned long long key =
        ((unsigned long long)__float_as_uint(bd) << 32) | (unsigned long long)bi;
    atomicMin(&keys[(size_t)side * L + lq], key);   // d2h > 0 -> bit-ordered
}

__device__ __forceinline__ float tanh_pos(float x) {
    const float t = __expf(-2.f * x);
    return (1.f - t) / (1.f + t);
}

// ---------------------------------------------------------------------------
// Kernel 2: gather nearest-node feats + 50->50->1 MLP. Thread = one query l.
// ---------------------------------------------------------------------------
__global__ __launch_bounds__(BLK) void pip_final(
    const float* __restrict__ red, const unsigned long long* __restrict__ keys,
    const float* __restrict__ g1_x, const float* __restrict__ g2_x,
    const float* __restrict__ W1, const float* __restrict__ b1,
    const float* __restrict__ W2, const float* __restrict__ b2,
    float* __restrict__ out, int L)
{
#pragma clang fp contract(off)
    const int l = blockIdx.x * BLK + threadIdx.x;
    if (l >= L) return;

    const unsigned idxL = (unsigned)(keys[l] & 0xffffffffull);
    const unsigned idxR = (unsigned)(keys[(size_t)L + l] & 0xffffffffull);
    const float normL = red[(size_t)12 * L + (size_t)l] + EPS_;
    const float normR = red[(size_t)25 * L + (size_t)l] + EPS_;

    float x[50];
    {
        const float4* f = (const float4*)(g1_x + (size_t)idxL * DG);
        const float4 f0 = f[0], f1 = f[1], f2 = f[2];
        x[0] = f0.x; x[1] = f0.y; x[2]  = f0.z; x[3]  = f0.w;
        x[4] = f1.x; x[5] = f1.y; x[6]  = f1.z; x[7]  = f1.w;
        x[8] = f2.x; x[9] = f2.y; x[10] = f2.z; x[11] = f2.w;
    }
#pragma unroll
    for (int k = 0; k < DG; ++k) x[12 + k] = red[(size_t)k * L + (size_t)l] / normL;
    x[24] = tanh_pos(normL);
    {
        const float4* f = (const float4*)(g2_x + (size_t)idxR * DG);
        const float4 f0 = f[0], f1 = f[1], f2 = f[2];
        x[25] = f0.x; x[26] = f0.y; x[27] = f0.z; x[28] = f0.w;
        x[29] = f1.x; x[30] = f1.y; x[31] = f1.z; x[32] = f1.w;
        x[33] = f2.x; x[34] = f2.y; x[35] = f2.z; x[36] = f2.w;
    }
#pragma unroll
    for (int k = 0; k < DG; ++k) x[37 + k] = red[(size_t)(13 + k) * L + (size_t)l] / normR;
    x[49] = tanh_pos(normR);

    float h[50];
#pragma unroll
    for (int j = 0; j < 50; ++j) h[j] = b1[j];
#pragma unroll
    for (int k = 0; k < 50; ++k) {
        const float xk = x[k];
#pragma unroll
        for (int j = 0; j < 50; ++j) h[j] = fmaf(xk, W1[k * 50 + j], h[j]);
    }
    float o = b2[0];
#pragma unroll
    for (int j = 0; j < 50; ++j) o = fmaf(fmaxf(h[j], 0.f), W2[j], o);
    out[l] = o;
}

// ---------------------------------------------------------------------------
extern "C" void kernel_launch(void* const* d_in, const int* in_sizes, int n_in,
                              void* d_out, int out_size, void* d_ws, size_t ws_size,
                              hipStream_t stream) {
    const float* locs_l = (const float*)d_in[0];
    const float* locs_r = (const float*)d_in[1];
    const float* g1_pos = (const float*)d_in[2];
    const float* g1_x   = (const float*)d_in[3];
    const float* g2_pos = (const float*)d_in[4];
    const float* g2_x   = (const float*)d_in[5];
    const float* s1_v   = (const float*)d_in[6];
    const float* s1_x   = (const float*)d_in[7];
    const float* s2_v   = (const float*)d_in[8];
    const float* s2_x   = (const float*)d_in[9];
    const float* W1     = (const float*)d_in[10];
    const float* b1     = (const float*)d_in[11];
    const float* W2     = (const float*)d_in[12];
    const float* b2     = (const float*)d_in[13];
    float* out = (float*)d_out;
    float* ws  = (float*)d_ws;

    const int L = in_sizes[0] / 3;   // 4096
    const int N = in_sizes[2] / 3;   // 40000
    const int T = (N + 31) / 32;     // 32-point tiles (1250, exact)
    const int P = T * 16;            // point pairs

    // ws layout (floats): [pk1s: 256T][pkps: 256T][fpk: 512T][red: 26L][keys: 2L u64]
    const size_t o_pkps = (size_t)256 * T;
    const size_t o_fpk  = (size_t)512 * T;
    const size_t o_red  = (size_t)1024 * T;

    const int CT = 20;                       // tiles per chunk
    const int SC = (T + CT - 1) / CT;        // 63 chunks -> grid 32 x 63 x 2

    float4* pk1s = (float4*)ws;
    float4* pkps = (float4*)(ws + o_pkps);
    int4*   fpk  = (int4*)(ws + o_fpk);
    float*  red  = ws + o_red;
    unsigned long long* keys = (unsigned long long*)(red + (size_t)26 * L);

    const int ptasks = 192 * T;              // 4P + 128T, P = 16T  (> 28L)
    pip_pack<<<dim3((ptasks + BLK - 1) / BLK), dim3(BLK), 0, stream>>>(
        g1_pos, g2_pos, s1_v, s1_x, s2_v, s2_x, pk1s, pkps, fpk, red, keys, N, T, L);

    pip_partial<<<dim3(L / 128, SC, 2), dim3(128), 0, stream>>>(
        locs_l, locs_r, pk1s, pkps, fpk, red, keys, L, T, CT, P);

    pip_final<<<dim3((L + BLK - 1) / BLK), dim3(BLK), 0, stream>>>(
        red, keys, g1_x, g2_x, W1, b1, W2, b2, out, L);
}